// Round 1
// baseline (6703.219 us; speedup 1.0000x reference)
//
#include <hip/hip_runtime.h>
#include <hip/hip_bf16.h>

#define NN 100000
#define NE 1600000
#define IN_DIM 33
#define HID 128
#define NG 128
#define NCLS 10

static __device__ __forceinline__ size_t szmul(int a, int b) {
    return (size_t)a * (size_t)b;
}

// ---------------- init ----------------
__global__ void k_init(float* deg, int* cnt, int* fill, float* gsum, int* gcnt, int n) {
    int i = blockIdx.x * blockDim.x + threadIdx.x;
    if (i < n) { deg[i] = 1.0f; cnt[i] = 0; fill[i] = 0; }
    if (i < NG * HID) gsum[i] = 0.0f;
    if (i < NG) gcnt[i] = 0;
}

// ---------------- degree ----------------
__global__ void k_edge_deg(const int* __restrict__ col, const float* __restrict__ w,
                           float* deg, int e) {
    int i = blockIdx.x * blockDim.x + threadIdx.x;
    if (i < e) atomicAdd(&deg[col[i]], w[i]);
}

__global__ void k_dinv(const float* __restrict__ deg, float* dinv, float* selfn, int n) {
    int i = blockIdx.x * blockDim.x + threadIdx.x;
    if (i < n) {
        float d = deg[i];
        float di = (d > 0.0f) ? (1.0f / sqrtf(d)) : 0.0f;
        dinv[i] = di;
        selfn[i] = di * di;
    }
}

// ---------------- CSR build ----------------
__global__ void k_edge_count(const int* __restrict__ col, int* cnt, int e) {
    int i = blockIdx.x * blockDim.x + threadIdx.x;
    if (i < e) atomicAdd(&cnt[col[i]], 1);
}

#define SCAN_B 1024
__global__ void k_scan1(const int* __restrict__ cnt, int* __restrict__ rowptr,
                        int* __restrict__ bsums, int n) {
    __shared__ int s[SCAN_B];
    int t = threadIdx.x;
    int i = blockIdx.x * SCAN_B + t;
    int v = (i < n) ? cnt[i] : 0;
    s[t] = v;
    __syncthreads();
    for (int o = 1; o < SCAN_B; o <<= 1) {
        int a = (t >= o) ? s[t - o] : 0;
        __syncthreads();
        s[t] += a;
        __syncthreads();
    }
    if (i < n) rowptr[i] = s[t] - v;          // exclusive within block
    if (t == SCAN_B - 1) bsums[blockIdx.x] = s[t];
}

__global__ void k_scan2(int* bsums, int nb) {
    if (threadIdx.x == 0 && blockIdx.x == 0) {
        int run = 0;
        for (int b = 0; b < nb; ++b) { int v = bsums[b]; bsums[b] = run; run += v; }
    }
}

__global__ void k_scan3(int* rowptr, const int* __restrict__ bsums, int n, int etot) {
    int i = blockIdx.x * blockDim.x + threadIdx.x;
    if (i < n) rowptr[i] += bsums[i >> 10];
    else if (i == n) rowptr[n] = etot;
}

__global__ void k_edge_scatter(const int* __restrict__ row, const int* __restrict__ col,
                               const float* __restrict__ w, const float* __restrict__ dinv,
                               const int* __restrict__ rowptr, int* fill,
                               int* __restrict__ csr_src, float* __restrict__ csr_w, int e) {
    int i = blockIdx.x * blockDim.x + threadIdx.x;
    if (i < e) {
        int r = row[i], c = col[i];
        float nw = dinv[r] * w[i] * dinv[c];
        int pos = rowptr[c] + atomicAdd(&fill[c], 1);
        csr_src[pos] = r;
        csr_w[pos] = nw;
    }
}

// ---------------- feature embedding: h = x @ We + be ----------------
__global__ __launch_bounds__(256) void k_feat0(const float* __restrict__ x,
                                               const float* __restrict__ We,
                                               const float* __restrict__ be,
                                               float* __restrict__ h, int n) {
    __shared__ float sX[2][IN_DIM];
    int node0 = blockIdx.x * 2;
    int tid = threadIdx.x;
    if (tid < 2 * IN_DIM) {
        int r = tid / IN_DIM, c = tid % IN_DIM;
        sX[r][c] = (node0 + r < n) ? x[szmul(node0 + r, IN_DIM) + c] : 0.0f;
    }
    __syncthreads();
    int r = tid >> 7;
    int f = tid & (HID - 1);
    int node = node0 + r;
    if (node < n) {
        float a = be[f];
#pragma unroll
        for (int k = 0; k < IN_DIM; ++k) a += sX[r][k] * We[k * HID + f];
        h[szmul(node, HID) + f] = a;
    }
}

// ---------------- GEMM: C = A @ W  (A: n x 128, W: 128 x 128) ----------------
__global__ __launch_bounds__(256) void k_gemm(const float* __restrict__ A,
                                              const float* __restrict__ W,
                                              float* __restrict__ C, int n) {
    __shared__ float sA[64][HID];   // 32 KiB
    int b0 = blockIdx.x * 64;
    int tid = threadIdx.x;
    // stage 64x128 tile: 2048 float4, 8 per thread
#pragma unroll
    for (int u = 0; u < 8; ++u) {
        int idx = u * 256 + tid;
        int r = idx >> 5, c4 = idx & 31;
        float4 v = make_float4(0.f, 0.f, 0.f, 0.f);
        if (b0 + r < n)
            v = *reinterpret_cast<const float4*>(A + szmul(b0 + r, HID) + c4 * 4);
        *reinterpret_cast<float4*>(&sA[r][c4 * 4]) = v;
    }
    __syncthreads();
    int ty = tid >> 5, tx = tid & 31;   // ty: 8 row groups, tx: 32 col groups of 4
    float acc[8][4] = {};
    for (int k0 = 0; k0 < HID; k0 += 4) {
        float4 a[8];
#pragma unroll
        for (int j = 0; j < 8; ++j)
            a[j] = *reinterpret_cast<const float4*>(&sA[ty * 8 + j][k0]);
        float4 wv[4];
#pragma unroll
        for (int kk = 0; kk < 4; ++kk)
            wv[kk] = *reinterpret_cast<const float4*>(&W[(size_t)(k0 + kk) * HID + tx * 4]);
#pragma unroll
        for (int kk = 0; kk < 4; ++kk) {
#pragma unroll
            for (int j = 0; j < 8; ++j) {
                float av = (kk == 0) ? a[j].x : (kk == 1) ? a[j].y : (kk == 2) ? a[j].z : a[j].w;
                acc[j][0] += av * wv[kk].x;
                acc[j][1] += av * wv[kk].y;
                acc[j][2] += av * wv[kk].z;
                acc[j][3] += av * wv[kk].w;
            }
        }
    }
#pragma unroll
    for (int j = 0; j < 8; ++j) {
        int r = b0 + ty * 8 + j;
        if (r < n) {
            float4 o = make_float4(acc[j][0], acc[j][1], acc[j][2], acc[j][3]);
            *reinterpret_cast<float4*>(&C[szmul(r, HID) + tx * 4]) = o;
        }
    }
}

// ---------------- aggregate: h[i] = relu(b + selfn[i]*t[i] + sum_e w_e * t[src_e]) ----
__global__ __launch_bounds__(128) void k_aggregate(const float* __restrict__ t,
                                                   const int* __restrict__ rowptr,
                                                   const int* __restrict__ csr_src,
                                                   const float* __restrict__ csr_w,
                                                   const float* __restrict__ selfn,
                                                   const float* __restrict__ bias,
                                                   float* __restrict__ hout, int n) {
    int i = blockIdx.x;
    if (i >= n) return;
    int f = threadIdx.x;
    __shared__ int s_src[64];
    __shared__ float s_w[64];
    int beg = rowptr[i], end = rowptr[i + 1];
    float acc = bias[f] + selfn[i] * t[szmul(i, HID) + f];
    for (int base = beg; base < end; base += 64) {
        int m = min(64, end - base);
        if (f < m) { s_src[f] = csr_src[base + f]; s_w[f] = csr_w[base + f]; }
        __syncthreads();
        for (int j = 0; j < m; ++j)
            acc += s_w[j] * t[szmul(s_src[j], HID) + f];
        __syncthreads();
    }
    hout[szmul(i, HID) + f] = fmaxf(acc, 0.0f);
}

// ---------------- pooling ----------------
__global__ void k_gcount(const int* __restrict__ batch, int* gcnt, int n) {
    int i = blockIdx.x * blockDim.x + threadIdx.x;
    if (i < n) atomicAdd(&gcnt[batch[i]], 1);
}

__global__ __launch_bounds__(128) void k_pool(const float* __restrict__ h,
                                              const int* __restrict__ batch,
                                              float* gsum, int n) {
    int f = threadIdx.x;
    int i0 = blockIdx.x * 32;
    int i1 = min(i0 + 32, n);
    if (i0 >= n) return;
    float acc = 0.0f;
    int cur = batch[i0];
    for (int i = i0; i < i1; ++i) {
        int g = batch[i];
        if (g != cur) { atomicAdd(&gsum[cur * HID + f], acc); acc = 0.0f; cur = g; }
        acc += h[szmul(i, HID) + f];
    }
    atomicAdd(&gsum[cur * HID + f], acc);
}

// ---------------- readout MLP ----------------
__global__ __launch_bounds__(128) void k_mlp(const float* __restrict__ gsum,
                                             const int* __restrict__ gcnt,
                                             const float* __restrict__ Wr1, const float* __restrict__ br1,
                                             const float* __restrict__ Wr2, const float* __restrict__ br2,
                                             const float* __restrict__ Wr3,
                                             float* __restrict__ out) {
    int g = blockIdx.x;
    int t = threadIdx.x;
    __shared__ float p[HID];
    __shared__ float r1[64];
    __shared__ float r2[32];
    float c = fmaxf((float)gcnt[g], 1.0f);
    p[t] = gsum[g * HID + t] / c;
    __syncthreads();
    if (t < 64) {
        float a = br1[t];
#pragma unroll 8
        for (int k = 0; k < HID; ++k) a += p[k] * Wr1[k * 64 + t];
        r1[t] = fmaxf(a, 0.0f);
    }
    __syncthreads();
    if (t < 32) {
        float a = br2[t];
#pragma unroll 8
        for (int k = 0; k < 64; ++k) a += r1[k] * Wr2[k * 32 + t];
        r2[t] = fmaxf(a, 0.0f);
    }
    __syncthreads();
    if (t < NCLS) {
        float a = 0.0f;
#pragma unroll
        for (int k = 0; k < 32; ++k) a += r2[k] * Wr3[k * NCLS + t];
        out[g * NCLS + t] = a;
    }
}

extern "C" void kernel_launch(void* const* d_in, const int* in_sizes, int n_in,
                              void* d_out, int out_size, void* d_ws, size_t ws_size,
                              hipStream_t stream) {
    const float* x     = (const float*)d_in[0];
    const int*   ei    = (const int*)d_in[1];
    const float* ew    = (const float*)d_in[2];
    const int*   batch = (const int*)d_in[3];
    const float* We  = (const float*)d_in[4];
    const float* be  = (const float*)d_in[5];
    const float* Wl[4] = { (const float*)d_in[6], (const float*)d_in[8],
                           (const float*)d_in[10], (const float*)d_in[12] };
    const float* bl[4] = { (const float*)d_in[7], (const float*)d_in[9],
                           (const float*)d_in[11], (const float*)d_in[13] };
    const float* Wr1 = (const float*)d_in[14];
    const float* br1 = (const float*)d_in[15];
    const float* Wr2 = (const float*)d_in[16];
    const float* br2 = (const float*)d_in[17];
    const float* Wr3 = (const float*)d_in[18];
    float* out = (float*)d_out;

    const int N = in_sizes[3];      // 100000
    const int E = in_sizes[2];      // 1600000
    const int* row = ei;
    const int* col = ei + E;

    // workspace layout
    char* w = (char*)d_ws;
    size_t off = 0;
    auto alloc = [&](size_t bytes) -> void* {
        void* p = w + off;
        off = (off + bytes + 255) & ~(size_t)255;
        return p;
    };
    float* deg     = (float*)alloc((size_t)N * 4);
    float* dinv    = (float*)alloc((size_t)N * 4);
    float* selfn   = (float*)alloc((size_t)N * 4);
    int*   cnt     = (int*)  alloc((size_t)N * 4);
    int*   rowptr  = (int*)  alloc((size_t)(N + 1) * 4);
    int*   fill    = (int*)  alloc((size_t)N * 4);
    int*   bsums   = (int*)  alloc(4096);
    int*   csr_src = (int*)  alloc((size_t)E * 4);
    float* csr_w   = (float*)alloc((size_t)E * 4);
    float* h       = (float*)alloc((size_t)N * HID * 4);
    float* t       = (float*)alloc((size_t)N * HID * 4);
    float* gsum    = (float*)alloc((size_t)NG * HID * 4);
    int*   gcnt    = (int*)  alloc((size_t)NG * 4);
    (void)ws_size;

    auto cdiv = [](int a, int b) { return (a + b - 1) / b; };

    k_init<<<cdiv(N, 256), 256, 0, stream>>>(deg, cnt, fill, gsum, gcnt, N);
    k_edge_deg<<<cdiv(E, 256), 256, 0, stream>>>(col, ew, deg, E);
    k_dinv<<<cdiv(N, 256), 256, 0, stream>>>(deg, dinv, selfn, N);
    k_edge_count<<<cdiv(E, 256), 256, 0, stream>>>(col, cnt, E);

    int nb = cdiv(N, SCAN_B);
    k_scan1<<<nb, SCAN_B, 0, stream>>>(cnt, rowptr, bsums, N);
    k_scan2<<<1, 64, 0, stream>>>(bsums, nb);
    k_scan3<<<cdiv(N + 1, 256), 256, 0, stream>>>(rowptr, bsums, N, E);
    k_edge_scatter<<<cdiv(E, 256), 256, 0, stream>>>(row, col, ew, dinv, rowptr, fill,
                                                     csr_src, csr_w, E);

    k_feat0<<<cdiv(N, 2), 256, 0, stream>>>(x, We, be, h, N);

    for (int l = 0; l < 4; ++l) {
        k_gemm<<<cdiv(N, 64), 256, 0, stream>>>(h, Wl[l], t, N);
        k_aggregate<<<N, 128, 0, stream>>>(t, rowptr, csr_src, csr_w, selfn, bl[l], h, N);
    }

    k_gcount<<<cdiv(N, 256), 256, 0, stream>>>(batch, gcnt, N);
    k_pool<<<cdiv(N, 32), 128, 0, stream>>>(h, batch, gsum, N);
    k_mlp<<<NG, HID, 0, stream>>>(gsum, gcnt, Wr1, br1, Wr2, br2, Wr3, out);

    (void)out_size; (void)n_in;
}

// Round 2
// 1317.808 us; speedup vs baseline: 5.0866x; 5.0866x over previous
//
#include <hip/hip_runtime.h>
#include <hip/hip_bf16.h>

#define NN 100000
#define NE 1600000
#define IN_DIM 33
#define HID 128
#define NG 128
#define NCLS 10

static __device__ __forceinline__ size_t szmul(int a, int b) {
    return (size_t)a * (size_t)b;
}

// ---------------- init ----------------
__global__ void k_init(float* deg, int* cnt, int* fill, float* gsum, int* gcnt, int n) {
    int i = blockIdx.x * blockDim.x + threadIdx.x;
    if (i < n) { deg[i] = 1.0f; cnt[i] = 0; fill[i] = 0; }
    if (i < NG * HID) gsum[i] = 0.0f;
    if (i < NG) gcnt[i] = 0;
}

// ---------------- degree ----------------
__global__ void k_edge_deg(const int* __restrict__ col, const float* __restrict__ w,
                           float* deg, int e) {
    int i = blockIdx.x * blockDim.x + threadIdx.x;
    if (i < e) atomicAdd(&deg[col[i]], w[i]);
}

__global__ void k_dinv(const float* __restrict__ deg, float* dinv, float* selfn, int n) {
    int i = blockIdx.x * blockDim.x + threadIdx.x;
    if (i < n) {
        float d = deg[i];
        float di = (d > 0.0f) ? (1.0f / sqrtf(d)) : 0.0f;
        dinv[i] = di;
        selfn[i] = di * di;
    }
}

// ---------------- CSR build ----------------
__global__ void k_edge_count(const int* __restrict__ col, int* cnt, int e) {
    int i = blockIdx.x * blockDim.x + threadIdx.x;
    if (i < e) atomicAdd(&cnt[col[i]], 1);
}

#define SCAN_B 1024
__global__ void k_scan1(const int* __restrict__ cnt, int* __restrict__ rowptr,
                        int* __restrict__ bsums, int n) {
    __shared__ int s[SCAN_B];
    int t = threadIdx.x;
    int i = blockIdx.x * SCAN_B + t;
    int v = (i < n) ? cnt[i] : 0;
    s[t] = v;
    __syncthreads();
    for (int o = 1; o < SCAN_B; o <<= 1) {
        int a = (t >= o) ? s[t - o] : 0;
        __syncthreads();
        s[t] += a;
        __syncthreads();
    }
    if (i < n) rowptr[i] = s[t] - v;          // exclusive within block
    if (t == SCAN_B - 1) bsums[blockIdx.x] = s[t];
}

__global__ void k_scan2(int* bsums, int nb) {
    if (threadIdx.x == 0 && blockIdx.x == 0) {
        int run = 0;
        for (int b = 0; b < nb; ++b) { int v = bsums[b]; bsums[b] = run; run += v; }
    }
}

__global__ void k_scan3(int* rowptr, const int* __restrict__ bsums, int n, int etot) {
    int i = blockIdx.x * blockDim.x + threadIdx.x;
    if (i < n) rowptr[i] += bsums[i >> 10];
    else if (i == n) rowptr[n] = etot;
}

__global__ void k_edge_scatter(const int* __restrict__ row, const int* __restrict__ col,
                               const float* __restrict__ w, const float* __restrict__ dinv,
                               const int* __restrict__ rowptr, int* fill,
                               int* __restrict__ csr_src, float* __restrict__ csr_w, int e) {
    int i = blockIdx.x * blockDim.x + threadIdx.x;
    if (i < e) {
        int r = row[i], c = col[i];
        float nw = dinv[r] * w[i] * dinv[c];
        int pos = rowptr[c] + atomicAdd(&fill[c], 1);
        csr_src[pos] = r;
        csr_w[pos] = nw;
    }
}

// ---------------- feature embedding: h = x @ We + be ----------------
__global__ __launch_bounds__(256) void k_feat0(const float* __restrict__ x,
                                               const float* __restrict__ We,
                                               const float* __restrict__ be,
                                               float* __restrict__ h, int n) {
    __shared__ float sX[2][IN_DIM];
    int node0 = blockIdx.x * 2;
    int tid = threadIdx.x;
    if (tid < 2 * IN_DIM) {
        int r = tid / IN_DIM, c = tid % IN_DIM;
        sX[r][c] = (node0 + r < n) ? x[szmul(node0 + r, IN_DIM) + c] : 0.0f;
    }
    __syncthreads();
    int r = tid >> 7;
    int f = tid & (HID - 1);
    int node = node0 + r;
    if (node < n) {
        float a = be[f];
#pragma unroll
        for (int k = 0; k < IN_DIM; ++k) a += sX[r][k] * We[k * HID + f];
        h[szmul(node, HID) + f] = a;
    }
}

// ---------------- GEMM: C = A @ W  (A: n x 128, W: 128 x 128) ----------------
// Spill-proof layout: 64 rows/block, 256 threads, thread = 8 rows x 4 cols.
// Accumulators are plain scalar float arrays with constant indices only.
__global__ __launch_bounds__(256) void k_gemm(const float* __restrict__ A,
                                              const float* __restrict__ W,
                                              float* __restrict__ C, int n) {
    __shared__ float sA[64][HID];   // 32 KiB
    int b0 = blockIdx.x * 64;
    int tid = threadIdx.x;
    // stage 64x128 tile: 2048 float4, 8 per thread
#pragma unroll
    for (int u = 0; u < 8; ++u) {
        int idx = u * 256 + tid;
        int r = idx >> 5, c4 = idx & 31;
        float4 v = make_float4(0.f, 0.f, 0.f, 0.f);
        if (b0 + r < n)
            v = *reinterpret_cast<const float4*>(A + szmul(b0 + r, HID) + c4 * 4);
        *reinterpret_cast<float4*>(&sA[r][c4 * 4]) = v;
    }
    __syncthreads();
    int ty = tid >> 5, tx = tid & 31;   // ty: 8 row-groups of 8, tx: 32 col-groups of 4
    float acc0[8], acc1[8], acc2[8], acc3[8];
#pragma unroll
    for (int j = 0; j < 8; ++j) { acc0[j] = 0.f; acc1[j] = 0.f; acc2[j] = 0.f; acc3[j] = 0.f; }
    const float* Wp = W + tx * 4;
#pragma unroll 2
    for (int k = 0; k < HID; ++k) {
        float4 w4 = *reinterpret_cast<const float4*>(Wp + (size_t)k * HID);
#pragma unroll
        for (int j = 0; j < 8; ++j) {
            float a = sA[ty * 8 + j][k];
            acc0[j] += a * w4.x;
            acc1[j] += a * w4.y;
            acc2[j] += a * w4.z;
            acc3[j] += a * w4.w;
        }
    }
#pragma unroll
    for (int j = 0; j < 8; ++j) {
        int r = b0 + ty * 8 + j;
        if (r < n) {
            float4 o = make_float4(acc0[j], acc1[j], acc2[j], acc3[j]);
            *reinterpret_cast<float4*>(&C[szmul(r, HID) + tx * 4]) = o;
        }
    }
}

// ---------------- aggregate: h[i] = relu(b + selfn[i]*t[i] + sum_e w_e * t[src_e]) ----
__global__ __launch_bounds__(128) void k_aggregate(const float* __restrict__ t,
                                                   const int* __restrict__ rowptr,
                                                   const int* __restrict__ csr_src,
                                                   const float* __restrict__ csr_w,
                                                   const float* __restrict__ selfn,
                                                   const float* __restrict__ bias,
                                                   float* __restrict__ hout, int n) {
    int i = blockIdx.x;
    if (i >= n) return;
    int f = threadIdx.x;
    __shared__ int s_src[64];
    __shared__ float s_w[64];
    int beg = rowptr[i], end = rowptr[i + 1];
    float acc = bias[f] + selfn[i] * t[szmul(i, HID) + f];
    for (int base = beg; base < end; base += 64) {
        int m = min(64, end - base);
        if (f < m) { s_src[f] = csr_src[base + f]; s_w[f] = csr_w[base + f]; }
        __syncthreads();
        for (int j = 0; j < m; ++j)
            acc += s_w[j] * t[szmul(s_src[j], HID) + f];
        __syncthreads();
    }
    hout[szmul(i, HID) + f] = fmaxf(acc, 0.0f);
}

// ---------------- pooling ----------------
__global__ void k_gcount(const int* __restrict__ batch, int* gcnt, int n) {
    int i = blockIdx.x * blockDim.x + threadIdx.x;
    if (i < n) atomicAdd(&gcnt[batch[i]], 1);
}

__global__ __launch_bounds__(128) void k_pool(const float* __restrict__ h,
                                              const int* __restrict__ batch,
                                              float* gsum, int n) {
    int f = threadIdx.x;
    int i0 = blockIdx.x * 32;
    int i1 = min(i0 + 32, n);
    if (i0 >= n) return;
    float acc = 0.0f;
    int cur = batch[i0];
    for (int i = i0; i < i1; ++i) {
        int g = batch[i];
        if (g != cur) { atomicAdd(&gsum[cur * HID + f], acc); acc = 0.0f; cur = g; }
        acc += h[szmul(i, HID) + f];
    }
    atomicAdd(&gsum[cur * HID + f], acc);
}

// ---------------- readout MLP ----------------
__global__ __launch_bounds__(128) void k_mlp(const float* __restrict__ gsum,
                                             const int* __restrict__ gcnt,
                                             const float* __restrict__ Wr1, const float* __restrict__ br1,
                                             const float* __restrict__ Wr2, const float* __restrict__ br2,
                                             const float* __restrict__ Wr3,
                                             float* __restrict__ out) {
    int g = blockIdx.x;
    int t = threadIdx.x;
    __shared__ float p[HID];
    __shared__ float r1[64];
    __shared__ float r2[32];
    float c = fmaxf((float)gcnt[g], 1.0f);
    p[t] = gsum[g * HID + t] / c;
    __syncthreads();
    if (t < 64) {
        float a = br1[t];
#pragma unroll 8
        for (int k = 0; k < HID; ++k) a += p[k] * Wr1[k * 64 + t];
        r1[t] = fmaxf(a, 0.0f);
    }
    __syncthreads();
    if (t < 32) {
        float a = br2[t];
#pragma unroll 8
        for (int k = 0; k < 64; ++k) a += r1[k] * Wr2[k * 32 + t];
        r2[t] = fmaxf(a, 0.0f);
    }
    __syncthreads();
    if (t < NCLS) {
        float a = 0.0f;
#pragma unroll
        for (int k = 0; k < 32; ++k) a += r2[k] * Wr3[k * NCLS + t];
        out[g * NCLS + t] = a;
    }
}

extern "C" void kernel_launch(void* const* d_in, const int* in_sizes, int n_in,
                              void* d_out, int out_size, void* d_ws, size_t ws_size,
                              hipStream_t stream) {
    const float* x     = (const float*)d_in[0];
    const int*   ei    = (const int*)d_in[1];
    const float* ew    = (const float*)d_in[2];
    const int*   batch = (const int*)d_in[3];
    const float* We  = (const float*)d_in[4];
    const float* be  = (const float*)d_in[5];
    const float* Wl[4] = { (const float*)d_in[6], (const float*)d_in[8],
                           (const float*)d_in[10], (const float*)d_in[12] };
    const float* bl[4] = { (const float*)d_in[7], (const float*)d_in[9],
                           (const float*)d_in[11], (const float*)d_in[13] };
    const float* Wr1 = (const float*)d_in[14];
    const float* br1 = (const float*)d_in[15];
    const float* Wr2 = (const float*)d_in[16];
    const float* br2 = (const float*)d_in[17];
    const float* Wr3 = (const float*)d_in[18];
    float* out = (float*)d_out;

    const int N = in_sizes[3];      // 100000
    const int E = in_sizes[2];      // 1600000
    const int* row = ei;
    const int* col = ei + E;

    // workspace layout
    char* w = (char*)d_ws;
    size_t off = 0;
    auto alloc = [&](size_t bytes) -> void* {
        void* p = w + off;
        off = (off + bytes + 255) & ~(size_t)255;
        return p;
    };
    float* deg     = (float*)alloc((size_t)N * 4);
    float* dinv    = (float*)alloc((size_t)N * 4);
    float* selfn   = (float*)alloc((size_t)N * 4);
    int*   cnt     = (int*)  alloc((size_t)N * 4);
    int*   rowptr  = (int*)  alloc((size_t)(N + 1) * 4);
    int*   fill    = (int*)  alloc((size_t)N * 4);
    int*   bsums   = (int*)  alloc(4096);
    int*   csr_src = (int*)  alloc((size_t)E * 4);
    float* csr_w   = (float*)alloc((size_t)E * 4);
    float* h       = (float*)alloc((size_t)N * HID * 4);
    float* t       = (float*)alloc((size_t)N * HID * 4);
    float* gsum    = (float*)alloc((size_t)NG * HID * 4);
    int*   gcnt    = (int*)  alloc((size_t)NG * 4);
    (void)ws_size;

    auto cdiv = [](int a, int b) { return (a + b - 1) / b; };

    k_init<<<cdiv(N, 256), 256, 0, stream>>>(deg, cnt, fill, gsum, gcnt, N);
    k_edge_deg<<<cdiv(E, 256), 256, 0, stream>>>(col, ew, deg, E);
    k_dinv<<<cdiv(N, 256), 256, 0, stream>>>(deg, dinv, selfn, N);
    k_edge_count<<<cdiv(E, 256), 256, 0, stream>>>(col, cnt, E);

    int nb = cdiv(N, SCAN_B);
    k_scan1<<<nb, SCAN_B, 0, stream>>>(cnt, rowptr, bsums, N);
    k_scan2<<<1, 64, 0, stream>>>(bsums, nb);
    k_scan3<<<cdiv(N + 1, 256), 256, 0, stream>>>(rowptr, bsums, N, E);
    k_edge_scatter<<<cdiv(E, 256), 256, 0, stream>>>(row, col, ew, dinv, rowptr, fill,
                                                     csr_src, csr_w, E);

    k_feat0<<<cdiv(N, 2), 256, 0, stream>>>(x, We, be, h, N);

    for (int l = 0; l < 4; ++l) {
        k_gemm<<<cdiv(N, 64), 256, 0, stream>>>(h, Wl[l], t, N);
        k_aggregate<<<N, 128, 0, stream>>>(t, rowptr, csr_src, csr_w, selfn, bl[l], h, N);
    }

    k_gcount<<<cdiv(N, 256), 256, 0, stream>>>(batch, gcnt, N);
    k_pool<<<cdiv(N, 32), 128, 0, stream>>>(h, batch, gsum, N);
    k_mlp<<<NG, HID, 0, stream>>>(gsum, gcnt, Wr1, br1, Wr2, br2, Wr3, out);

    (void)out_size; (void)n_in;
}

// Round 3
// 1040.544 us; speedup vs baseline: 6.4420x; 1.2665x over previous
//
#include <hip/hip_runtime.h>
#include <hip/hip_bf16.h>

#define NN 100000
#define NE 1600000
#define IN_DIM 33
#define HID 128
#define NG 128
#define NCLS 10

static __device__ __forceinline__ size_t szmul(int a, int b) {
    return (size_t)a * (size_t)b;
}

// ---------------- init ----------------
__global__ void k_init(int* cnt, int* fill, float* gsum, int n) {
    int i = blockIdx.x * blockDim.x + threadIdx.x;
    if (i < n) { cnt[i] = 0; fill[i] = 0; }
    if (i < NG * HID) gsum[i] = 0.0f;
}

// ---------------- CSR build ----------------
__global__ void k_edge_count(const int* __restrict__ col, int* cnt, int e) {
    int i = blockIdx.x * blockDim.x + threadIdx.x;
    if (i < e) atomicAdd(&cnt[col[i]], 1);
}

#define SCAN_B 1024
__global__ void k_scan1(const int* __restrict__ cnt, int* __restrict__ rowptr,
                        int* __restrict__ bsums, int n) {
    __shared__ int s[SCAN_B];
    int t = threadIdx.x;
    int i = blockIdx.x * SCAN_B + t;
    int v = (i < n) ? cnt[i] : 0;
    s[t] = v;
    __syncthreads();
    for (int o = 1; o < SCAN_B; o <<= 1) {
        int a = (t >= o) ? s[t - o] : 0;
        __syncthreads();
        s[t] += a;
        __syncthreads();
    }
    if (i < n) rowptr[i] = s[t] - v;          // exclusive within block
    if (t == SCAN_B - 1) bsums[blockIdx.x] = s[t];
}

__global__ void k_scan2(int* bsums, int nb) {
    if (threadIdx.x == 0 && blockIdx.x == 0) {
        int run = 0;
        for (int b = 0; b < nb; ++b) { int v = bsums[b]; bsums[b] = run; run += v; }
    }
}

__global__ void k_scan3(int* rowptr, const int* __restrict__ bsums, int n, int etot) {
    int i = blockIdx.x * blockDim.x + threadIdx.x;
    if (i < n) rowptr[i] += bsums[i >> 10];
    else if (i == n) rowptr[n] = etot;
}

// scatter RAW weights; normalization happens after degree is known
__global__ void k_edge_scatter(const int* __restrict__ row, const int* __restrict__ col,
                               const float* __restrict__ w,
                               const int* __restrict__ rowptr, int* fill,
                               int* __restrict__ csr_src, float* __restrict__ csr_w, int e) {
    int i = blockIdx.x * blockDim.x + threadIdx.x;
    if (i < e) {
        int c = col[i];
        int pos = rowptr[c] + atomicAdd(&fill[c], 1);
        csr_src[pos] = row[i];
        csr_w[pos] = w[i];
    }
}

// deg[i] = 1 (self loop) + sum of raw weights into i; dinv = deg^-1/2
__global__ void k_deg(const int* __restrict__ rowptr, const float* __restrict__ csr_w,
                      float* __restrict__ dinv, float* __restrict__ selfn, int n) {
    int i = blockIdx.x * blockDim.x + threadIdx.x;
    if (i >= n) return;
    int beg = rowptr[i], end = rowptr[i + 1];
    float d = 1.0f;
    for (int e = beg; e < end; ++e) d += csr_w[e];
    float di = (d > 0.0f) ? (1.0f / sqrtf(d)) : 0.0f;
    dinv[i] = di;
    selfn[i] = di * di;
}

// csr_w[e] = dinv[src] * w * dinv[dst]
__global__ void k_norm(const int* __restrict__ rowptr, const int* __restrict__ csr_src,
                       float* __restrict__ csr_w, const float* __restrict__ dinv, int n) {
    int i = blockIdx.x * blockDim.x + threadIdx.x;
    if (i >= n) return;
    float dc = dinv[i];
    int beg = rowptr[i], end = rowptr[i + 1];
    for (int e = beg; e < end; ++e)
        csr_w[e] = dinv[csr_src[e]] * csr_w[e] * dc;
}

// ---------------- feature embedding: h = x @ We + be ----------------
__global__ __launch_bounds__(256) void k_feat0(const float* __restrict__ x,
                                               const float* __restrict__ We,
                                               const float* __restrict__ be,
                                               float* __restrict__ h, int n) {
    __shared__ float sX[2][IN_DIM];
    int node0 = blockIdx.x * 2;
    int tid = threadIdx.x;
    if (tid < 2 * IN_DIM) {
        int r = tid / IN_DIM, c = tid % IN_DIM;
        sX[r][c] = (node0 + r < n) ? x[szmul(node0 + r, IN_DIM) + c] : 0.0f;
    }
    __syncthreads();
    int r = tid >> 7;
    int f = tid & (HID - 1);
    int node = node0 + r;
    if (node < n) {
        float a = be[f];
#pragma unroll
        for (int k = 0; k < IN_DIM; ++k) a += sX[r][k] * We[k * HID + f];
        h[szmul(node, HID) + f] = a;
    }
}

// ---------------- GEMM: C = A @ W  (A: n x 128, W: 128 x 128) ----------------
__global__ __launch_bounds__(256) void k_gemm(const float* __restrict__ A,
                                              const float* __restrict__ W,
                                              float* __restrict__ C, int n) {
    __shared__ float sA[64][HID];   // 32 KiB
    int b0 = blockIdx.x * 64;
    int tid = threadIdx.x;
#pragma unroll
    for (int u = 0; u < 8; ++u) {
        int idx = u * 256 + tid;
        int r = idx >> 5, c4 = idx & 31;
        float4 v = make_float4(0.f, 0.f, 0.f, 0.f);
        if (b0 + r < n)
            v = *reinterpret_cast<const float4*>(A + szmul(b0 + r, HID) + c4 * 4);
        *reinterpret_cast<float4*>(&sA[r][c4 * 4]) = v;
    }
    __syncthreads();
    int ty = tid >> 5, tx = tid & 31;
    float acc0[8], acc1[8], acc2[8], acc3[8];
#pragma unroll
    for (int j = 0; j < 8; ++j) { acc0[j] = 0.f; acc1[j] = 0.f; acc2[j] = 0.f; acc3[j] = 0.f; }
    const float* Wp = W + tx * 4;
#pragma unroll 2
    for (int k = 0; k < HID; ++k) {
        float4 w4 = *reinterpret_cast<const float4*>(Wp + (size_t)k * HID);
#pragma unroll
        for (int j = 0; j < 8; ++j) {
            float a = sA[ty * 8 + j][k];
            acc0[j] += a * w4.x;
            acc1[j] += a * w4.y;
            acc2[j] += a * w4.z;
            acc3[j] += a * w4.w;
        }
    }
#pragma unroll
    for (int j = 0; j < 8; ++j) {
        int r = b0 + ty * 8 + j;
        if (r < n) {
            float4 o = make_float4(acc0[j], acc1[j], acc2[j], acc3[j]);
            *reinterpret_cast<float4*>(&C[szmul(r, HID) + tx * 4]) = o;
        }
    }
}

// ---------------- aggregate: h[i] = relu(b + selfn[i]*t[i] + sum_e w_e * t[src_e]) ----
__global__ __launch_bounds__(128) void k_aggregate(const float* __restrict__ t,
                                                   const int* __restrict__ rowptr,
                                                   const int* __restrict__ csr_src,
                                                   const float* __restrict__ csr_w,
                                                   const float* __restrict__ selfn,
                                                   const float* __restrict__ bias,
                                                   float* __restrict__ hout, int n) {
    int i = blockIdx.x;
    if (i >= n) return;
    int f = threadIdx.x;
    __shared__ int s_src[64];
    __shared__ float s_w[64];
    int beg = rowptr[i], end = rowptr[i + 1];
    float acc = bias[f] + selfn[i] * t[szmul(i, HID) + f];
    for (int base = beg; base < end; base += 64) {
        int m = min(64, end - base);
        if (f < m) { s_src[f] = csr_src[base + f]; s_w[f] = csr_w[base + f]; }
        __syncthreads();
        for (int j = 0; j < m; ++j)
            acc += s_w[j] * t[szmul(s_src[j], HID) + f];
        __syncthreads();
    }
    hout[szmul(i, HID) + f] = fmaxf(acc, 0.0f);
}

// ---------------- pooling ----------------
// batch is sorted: count via binary search, no atomics
__global__ void k_gcount_bs(const int* __restrict__ batch, int* gcnt, int n) {
    int g = threadIdx.x;
    if (g >= NG) return;
    int lo = 0, hi = n;
    while (lo < hi) { int mid = (lo + hi) >> 1; if (batch[mid] < g) lo = mid + 1; else hi = mid; }
    int start = lo;
    lo = 0; hi = n;
    while (lo < hi) { int mid = (lo + hi) >> 1; if (batch[mid] < g + 1) lo = mid + 1; else hi = mid; }
    gcnt[g] = lo - start;
}

__global__ __launch_bounds__(128) void k_pool(const float* __restrict__ h,
                                              const int* __restrict__ batch,
                                              float* gsum, int n) {
    int f = threadIdx.x;
    int i0 = blockIdx.x * 32;
    int i1 = min(i0 + 32, n);
    if (i0 >= n) return;
    float acc = 0.0f;
    int cur = batch[i0];
    for (int i = i0; i < i1; ++i) {
        int g = batch[i];
        if (g != cur) { atomicAdd(&gsum[cur * HID + f], acc); acc = 0.0f; cur = g; }
        acc += h[szmul(i, HID) + f];
    }
    atomicAdd(&gsum[cur * HID + f], acc);
}

// ---------------- readout MLP ----------------
__global__ __launch_bounds__(128) void k_mlp(const float* __restrict__ gsum,
                                             const int* __restrict__ gcnt,
                                             const float* __restrict__ Wr1, const float* __restrict__ br1,
                                             const float* __restrict__ Wr2, const float* __restrict__ br2,
                                             const float* __restrict__ Wr3,
                                             float* __restrict__ out) {
    int g = blockIdx.x;
    int t = threadIdx.x;
    __shared__ float p[HID];
    __shared__ float r1[64];
    __shared__ float r2[32];
    float c = fmaxf((float)gcnt[g], 1.0f);
    p[t] = gsum[g * HID + t] / c;
    __syncthreads();
    if (t < 64) {
        float a = br1[t];
#pragma unroll 8
        for (int k = 0; k < HID; ++k) a += p[k] * Wr1[k * 64 + t];
        r1[t] = fmaxf(a, 0.0f);
    }
    __syncthreads();
    if (t < 32) {
        float a = br2[t];
#pragma unroll 8
        for (int k = 0; k < 64; ++k) a += r1[k] * Wr2[k * 32 + t];
        r2[t] = fmaxf(a, 0.0f);
    }
    __syncthreads();
    if (t < NCLS) {
        float a = 0.0f;
#pragma unroll
        for (int k = 0; k < 32; ++k) a += r2[k] * Wr3[k * NCLS + t];
        out[g * NCLS + t] = a;
    }
}

extern "C" void kernel_launch(void* const* d_in, const int* in_sizes, int n_in,
                              void* d_out, int out_size, void* d_ws, size_t ws_size,
                              hipStream_t stream) {
    const float* x     = (const float*)d_in[0];
    const int*   ei    = (const int*)d_in[1];
    const float* ew    = (const float*)d_in[2];
    const int*   batch = (const int*)d_in[3];
    const float* We  = (const float*)d_in[4];
    const float* be  = (const float*)d_in[5];
    const float* Wl[4] = { (const float*)d_in[6], (const float*)d_in[8],
                           (const float*)d_in[10], (const float*)d_in[12] };
    const float* bl[4] = { (const float*)d_in[7], (const float*)d_in[9],
                           (const float*)d_in[11], (const float*)d_in[13] };
    const float* Wr1 = (const float*)d_in[14];
    const float* br1 = (const float*)d_in[15];
    const float* Wr2 = (const float*)d_in[16];
    const float* br2 = (const float*)d_in[17];
    const float* Wr3 = (const float*)d_in[18];
    float* out = (float*)d_out;

    const int N = in_sizes[3];      // 100000
    const int E = in_sizes[2];      // 1600000
    const int* row = ei;
    const int* col = ei + E;

    // workspace layout
    char* w = (char*)d_ws;
    size_t off = 0;
    auto alloc = [&](size_t bytes) -> void* {
        void* p = w + off;
        off = (off + bytes + 255) & ~(size_t)255;
        return p;
    };
    float* dinv    = (float*)alloc((size_t)N * 4);
    float* selfn   = (float*)alloc((size_t)N * 4);
    int*   cnt     = (int*)  alloc((size_t)N * 4);
    int*   rowptr  = (int*)  alloc((size_t)(N + 1) * 4);
    int*   fill    = (int*)  alloc((size_t)N * 4);
    int*   bsums   = (int*)  alloc(4096);
    int*   csr_src = (int*)  alloc((size_t)E * 4);
    float* csr_w   = (float*)alloc((size_t)E * 4);
    float* h       = (float*)alloc((size_t)N * HID * 4);
    float* t       = (float*)alloc((size_t)N * HID * 4);
    float* gsum    = (float*)alloc((size_t)NG * HID * 4);
    int*   gcnt    = (int*)  alloc((size_t)NG * 4);
    (void)ws_size;

    auto cdiv = [](int a, int b) { return (a + b - 1) / b; };

    k_init<<<cdiv(N, 256), 256, 0, stream>>>(cnt, fill, gsum, N);
    k_edge_count<<<cdiv(E, 256), 256, 0, stream>>>(col, cnt, E);

    int nb = cdiv(N, SCAN_B);
    k_scan1<<<nb, SCAN_B, 0, stream>>>(cnt, rowptr, bsums, N);
    k_scan2<<<1, 64, 0, stream>>>(bsums, nb);
    k_scan3<<<cdiv(N + 1, 256), 256, 0, stream>>>(rowptr, bsums, N, E);
    k_edge_scatter<<<cdiv(E, 256), 256, 0, stream>>>(row, col, ew, rowptr, fill,
                                                     csr_src, csr_w, E);
    k_deg<<<cdiv(N, 256), 256, 0, stream>>>(rowptr, csr_w, dinv, selfn, N);
    k_norm<<<cdiv(N, 256), 256, 0, stream>>>(rowptr, csr_src, csr_w, dinv, N);

    k_feat0<<<cdiv(N, 2), 256, 0, stream>>>(x, We, be, h, N);

    for (int l = 0; l < 4; ++l) {
        k_gemm<<<cdiv(N, 64), 256, 0, stream>>>(h, Wl[l], t, N);
        k_aggregate<<<N, 128, 0, stream>>>(t, rowptr, csr_src, csr_w, selfn, bl[l], h, N);
    }

    k_gcount_bs<<<1, 128, 0, stream>>>(batch, gcnt, N);
    k_pool<<<cdiv(N, 32), 128, 0, stream>>>(h, batch, gsum, N);
    k_mlp<<<NG, HID, 0, stream>>>(gsum, gcnt, Wr1, br1, Wr2, br2, Wr3, out);

    (void)out_size; (void)n_in;
}